// Round 1
// baseline (100.701 us; speedup 1.0000x reference)
//
#include <hip/hip_runtime.h>
#include <hip/hip_bf16.h>

#define BB 8
#define SS 8192
#define FF 512
#define EE 128
#define CC 1000

typedef __bf16 bf16x8 __attribute__((ext_vector_type(8)));
typedef float  f32x4  __attribute__((ext_vector_type(4)));

// ---------------- K0: transpose-convert W (F,E) f32 -> Wt (E,F) bf16 ----------------
__global__ void k0_wt(const float* __restrict__ W, __bf16* __restrict__ Wt) {
    int idx = blockIdx.x * 256 + threadIdx.x;   // 65536 = F*E
    int e = idx & (EE - 1);
    int f = idx >> 7;
    Wt[e * FF + f] = (__bf16)W[f * EE + e];
}

// ---------------- K1: scores[b][s] = -|| (x_b - support_x[b,s]) @ W || ----------------
// grid = 512 blocks (64 per b), 256 threads (4 waves). Tile: 128 rows x 128 cols(E), K=512.
__global__ __launch_bounds__(256) void k1_scores(
    const float* __restrict__ x,          // (B,F)
    const float* __restrict__ sx,         // (B,S,F)
    const __bf16* __restrict__ Wt,        // (E,F) bf16
    float* __restrict__ scores)           // (B,S)
{
    // LDS: A = diff tile [kgrp][row][8k] bf16, double buffered; B = W tile [kgrp][e][8k]
    __shared__ __bf16 lA[2][4][128][8];
    __shared__ __bf16 lB[2][4][128][8];
    __shared__ float  scp[2][128];

    const int tid   = threadIdx.x;
    const int b     = blockIdx.x >> 6;
    const int srow0 = (blockIdx.x & 63) << 7;
    const float* Xb = sx + ((size_t)b * SS + srow0) * FF;
    const float* xb = x + b * FF;

    const int row  = tid >> 1;        // 0..127 (also used as 'e' for B staging)
    const int kh   = tid & 1;         // which 16-float half of the 32-k step
    const int lane = tid & 63;
    const int w    = tid >> 6;        // wave 0..3
    const int wrow = (w >> 1) * 64;
    const int wcol = (w & 1) * 64;
    const int lg   = lane >> 4;       // k-group 0..3
    const int lr   = lane & 15;

    f32x4 acc[4][4];
    #pragma unroll
    for (int m = 0; m < 4; m++)
        #pragma unroll
        for (int n = 0; n < 4; n++) { f32x4 z = {0.f, 0.f, 0.f, 0.f}; acc[m][n] = z; }

    float4 sReg[4], xReg[4];

    auto LOADT = [&](int t) {
        const float* pS = Xb + (size_t)row * FF + t * 32 + kh * 16;
        const float* pX = xb + t * 32 + kh * 16;
        #pragma unroll
        for (int i = 0; i < 4; i++) {
            sReg[i] = *(const float4*)(pS + 4 * i);
            xReg[i] = *(const float4*)(pX + 4 * i);
        }
    };
    auto WRITET = [&](int buf) {
        __bf16 d[16];
        #pragma unroll
        for (int i = 0; i < 4; i++) {
            d[4 * i + 0] = (__bf16)(xReg[i].x - sReg[i].x);
            d[4 * i + 1] = (__bf16)(xReg[i].y - sReg[i].y);
            d[4 * i + 2] = (__bf16)(xReg[i].z - sReg[i].z);
            d[4 * i + 3] = (__bf16)(xReg[i].w - sReg[i].w);
        }
        *(bf16x8*)&lA[buf][kh * 2 + 0][row][0] = *(bf16x8*)&d[0];
        *(bf16x8*)&lA[buf][kh * 2 + 1][row][0] = *(bf16x8*)&d[8];
    };
    auto STAGEB = [&](int buf, int t) {
        const __bf16* pW = Wt + (size_t)row * FF + t * 32 + kh * 16;  // row == e here
        bf16x8 w0 = *(const bf16x8*)(pW);
        bf16x8 w1 = *(const bf16x8*)(pW + 8);
        *(bf16x8*)&lB[buf][kh * 2 + 0][row][0] = w0;
        *(bf16x8*)&lB[buf][kh * 2 + 1][row][0] = w1;
    };

    // prologue: stage K-step 0 into buffer 0
    LOADT(0);
    STAGEB(0, 0);
    WRITET(0);
    __syncthreads();

    for (int t = 0; t < 16; t++) {
        const int cur = t & 1;
        if (t < 15) {                    // issue next-tile global loads early (latency hides under MFMA)
            LOADT(t + 1);
            STAGEB(cur ^ 1, t + 1);
        }
        bf16x8 af[4], bfr[4];
        #pragma unroll
        for (int m = 0; m < 4; m++)
            af[m] = *(const bf16x8*)&lA[cur][lg][wrow + m * 16 + lr][0];
        #pragma unroll
        for (int n = 0; n < 4; n++)
            bfr[n] = *(const bf16x8*)&lB[cur][lg][wcol + n * 16 + lr][0];
        #pragma unroll
        for (int m = 0; m < 4; m++)
            #pragma unroll
            for (int n = 0; n < 4; n++)
                acc[m][n] = __builtin_amdgcn_mfma_f32_16x16x32_bf16(af[m], bfr[n], acc[m][n], 0, 0, 0);
        if (t < 15) WRITET(cur ^ 1);     // convert + LDS-write next A tile after MFMAs
        __syncthreads();
    }

    // epilogue: per-row sum of squares over E, then cross-lane/cross-wave reduce
    // C/D layout: col = wcol + n*16 + lr ; row = wrow + m*16 + lg*4 + j
    float rp[4][4];
    #pragma unroll
    for (int m = 0; m < 4; m++)
        #pragma unroll
        for (int j = 0; j < 4; j++) {
            float s = 0.f;
            #pragma unroll
            for (int n = 0; n < 4; n++) { float v = acc[m][n][j]; s += v * v; }
            rp[m][j] = s;
        }
    #pragma unroll
    for (int mask = 1; mask < 16; mask <<= 1)
        #pragma unroll
        for (int m = 0; m < 4; m++)
            #pragma unroll
            for (int j = 0; j < 4; j++)
                rp[m][j] += __shfl_xor(rp[m][j], mask);

    if (lr == 0) {
        #pragma unroll
        for (int m = 0; m < 4; m++)
            #pragma unroll
            for (int j = 0; j < 4; j++)
                scp[w & 1][wrow + m * 16 + lg * 4 + j] = rp[m][j];
    }
    __syncthreads();
    if (tid < 128) {
        float sum = scp[0][tid] + scp[1][tid];
        scores[(size_t)b * SS + srow0 + tid] = -sqrtf(sum);
    }
}

// ---------------- K3: partial weighted sums over support_y ----------------
// grid = 1024 blocks (b = bid>>7, chunk = bid&127 of 64 rows), 256 threads
__global__ __launch_bounds__(256) void k3_wsum(
    const float* __restrict__ scores,    // (B,S)
    const float* __restrict__ y,         // (B,S,C)
    float* __restrict__ pout,            // (B,128,C)
    float* __restrict__ pden)            // (B,128)
{
    __shared__ float wv[64];
    const int b  = blockIdx.x >> 7;
    const int ch = blockIdx.x & 127;
    const int s0 = ch * 64;
    const int t  = threadIdx.x;

    if (t < 64) wv[t] = expf(scores[b * SS + s0 + t]);
    __syncthreads();

    if (t < 250) {
        float a0 = 0.f, a1 = 0.f, a2 = 0.f, a3 = 0.f;
        const float* base = y + ((size_t)b * SS + s0) * CC + t * 4;
        #pragma unroll 4
        for (int r = 0; r < 64; r++) {
            float4 v = *(const float4*)(base + (size_t)r * CC);
            float wgt = wv[r];
            a0 += wgt * v.x; a1 += wgt * v.y; a2 += wgt * v.z; a3 += wgt * v.w;
        }
        float4 res = {a0, a1, a2, a3};
        *(float4*)(pout + ((size_t)b * 128 + ch) * CC + t * 4) = res;
    }
    if (t == 0) {
        float d = 0.f;
        for (int r = 0; r < 64; r++) d += wv[r];
        pden[b * 128 + ch] = d;
    }
}

// ---------------- K4: final reduction ----------------
__global__ void k4_final(const float* __restrict__ pout, const float* __restrict__ pden,
                         float* __restrict__ out) {
    int idx = blockIdx.x * 256 + threadIdx.x;
    if (idx >= BB * CC) return;
    int b = idx / CC, c = idx % CC;
    float den = 0.f;
    for (int k = 0; k < 128; k++) den += pden[b * 128 + k];
    float num = 0.f;
    for (int k = 0; k < 128; k++) num += pout[((size_t)b * 128 + k) * CC + c];
    out[idx] = num / den;
}

extern "C" void kernel_launch(void* const* d_in, const int* in_sizes, int n_in,
                              void* d_out, int out_size, void* d_ws, size_t ws_size,
                              hipStream_t stream) {
    const float* x  = (const float*)d_in[0];
    const float* sx = (const float*)d_in[1];
    const float* sy = (const float*)d_in[2];
    const float* W  = (const float*)d_in[3];

    char* ws = (char*)d_ws;
    __bf16* Wt    = (__bf16*)(ws);                                   // 131072 B
    float*  scores = (float*)(ws + 131072);                          // 262144 B
    float*  pout   = (float*)(ws + 131072 + 262144);                 // 4096000 B
    float*  pden   = (float*)(ws + 131072 + 262144 + 4096000);       // 4096 B

    k0_wt<<<256, 256, 0, stream>>>(W, Wt);
    k1_scores<<<512, 256, 0, stream>>>(x, sx, Wt, scores);
    k3_wsum<<<1024, 256, 0, stream>>>(scores, sy, pout, pden);
    k4_final<<<32, 256, 0, stream>>>(pout, pden, (float*)d_out);
}

// Round 2
// 89.171 us; speedup vs baseline: 1.1293x; 1.1293x over previous
//
#include <hip/hip_runtime.h>
#include <hip/hip_bf16.h>

#define BB 8
#define SS 8192
#define FF 512
#define EE 128
#define CC 1000

typedef __bf16 bf16x8 __attribute__((ext_vector_type(8)));
typedef float  f32x4  __attribute__((ext_vector_type(4)));

// ---------------- K0: transpose-convert W (F,E) f32 -> Wt (E,F) bf16 ----------------
__global__ void k0_wt(const float* __restrict__ W, __bf16* __restrict__ Wt) {
    int idx = blockIdx.x * 256 + threadIdx.x;   // 65536 = F*E
    int e = idx & (EE - 1);
    int f = idx >> 7;
    Wt[e * FF + f] = (__bf16)W[f * EE + e];
}

// ---------------- FUSED: scores -> exp weights -> weighted partial sums ----------------
// grid = 512 blocks (b = bid>>6, chunk = bid&63 of 128 rows), 256 threads (4 waves)
__global__ __launch_bounds__(256) void k_fused(
    const float* __restrict__ x,          // (B,F)
    const float* __restrict__ sx,         // (B,S,F)
    const __bf16* __restrict__ Wt,        // (E,F) bf16
    const float* __restrict__ y,          // (B,S,C)
    float* __restrict__ pout,             // (B,64,C) partial numerators
    float* __restrict__ pden)             // (B,64)   partial denominators
{
    __shared__ __bf16 lA[2][4][128][8];
    __shared__ __bf16 lB[2][4][128][8];
    __shared__ float  scp[2][128];
    __shared__ float  wv[128];

    const int tid   = threadIdx.x;
    const int b     = blockIdx.x >> 6;
    const int chunk = blockIdx.x & 63;
    const int srow0 = chunk << 7;
    const float* Xb = sx + ((size_t)b * SS + srow0) * FF;
    const float* xb = x + b * FF;

    const int row  = tid >> 1;        // 0..127 (also 'e' for B staging)
    const int kh   = tid & 1;         // 16-float half of the 32-k step
    const int lane = tid & 63;
    const int w    = tid >> 6;        // wave 0..3
    const int wrow = (w >> 1) * 64;
    const int wcol = (w & 1) * 64;
    const int lg   = lane >> 4;       // k-group 0..3
    const int lr   = lane & 15;

    f32x4 acc[4][4];
    #pragma unroll
    for (int m = 0; m < 4; m++)
        #pragma unroll
        for (int n = 0; n < 4; n++) { f32x4 z = {0.f, 0.f, 0.f, 0.f}; acc[m][n] = z; }

    float4 sReg[4], xReg[4];

    auto LOADT = [&](int t) {
        const float* pS = Xb + (size_t)row * FF + t * 32 + kh * 16;
        const float* pX = xb + t * 32 + kh * 16;
        #pragma unroll
        for (int i = 0; i < 4; i++) {
            sReg[i] = *(const float4*)(pS + 4 * i);
            xReg[i] = *(const float4*)(pX + 4 * i);
        }
    };
    auto WRITET = [&](int buf) {
        __bf16 d[16];
        #pragma unroll
        for (int i = 0; i < 4; i++) {
            d[4 * i + 0] = (__bf16)(xReg[i].x - sReg[i].x);
            d[4 * i + 1] = (__bf16)(xReg[i].y - sReg[i].y);
            d[4 * i + 2] = (__bf16)(xReg[i].z - sReg[i].z);
            d[4 * i + 3] = (__bf16)(xReg[i].w - sReg[i].w);
        }
        *(bf16x8*)&lA[buf][kh * 2 + 0][row][0] = *(bf16x8*)&d[0];
        *(bf16x8*)&lA[buf][kh * 2 + 1][row][0] = *(bf16x8*)&d[8];
    };
    auto STAGEB = [&](int buf, int t) {
        const __bf16* pW = Wt + (size_t)row * FF + t * 32 + kh * 16;  // row == e here
        bf16x8 w0 = *(const bf16x8*)(pW);
        bf16x8 w1 = *(const bf16x8*)(pW + 8);
        *(bf16x8*)&lB[buf][kh * 2 + 0][row][0] = w0;
        *(bf16x8*)&lB[buf][kh * 2 + 1][row][0] = w1;
    };

    // ---- Phase 1: diff-GEMM over K=512 ----
    LOADT(0);
    STAGEB(0, 0);
    WRITET(0);
    __syncthreads();

    for (int t = 0; t < 16; t++) {
        const int cur = t & 1;
        if (t < 15) {
            LOADT(t + 1);
            STAGEB(cur ^ 1, t + 1);
        }
        bf16x8 af[4], bfr[4];
        #pragma unroll
        for (int m = 0; m < 4; m++)
            af[m] = *(const bf16x8*)&lA[cur][lg][wrow + m * 16 + lr][0];
        #pragma unroll
        for (int n = 0; n < 4; n++)
            bfr[n] = *(const bf16x8*)&lB[cur][lg][wcol + n * 16 + lr][0];
        #pragma unroll
        for (int m = 0; m < 4; m++)
            #pragma unroll
            for (int n = 0; n < 4; n++)
                acc[m][n] = __builtin_amdgcn_mfma_f32_16x16x32_bf16(af[m], bfr[n], acc[m][n], 0, 0, 0);
        if (t < 15) WRITET(cur ^ 1);
        __syncthreads();
    }

    // ---- Epilogue: per-row ||.||^2 -> wv[row] = exp(-sqrt(.)) ----
    // C/D layout: col = wcol + n*16 + lr ; row = wrow + m*16 + lg*4 + j
    float rp[4][4];
    #pragma unroll
    for (int m = 0; m < 4; m++)
        #pragma unroll
        for (int j = 0; j < 4; j++) {
            float s = 0.f;
            #pragma unroll
            for (int n = 0; n < 4; n++) { float v = acc[m][n][j]; s += v * v; }
            rp[m][j] = s;
        }
    #pragma unroll
    for (int mask = 1; mask < 16; mask <<= 1)
        #pragma unroll
        for (int m = 0; m < 4; m++)
            #pragma unroll
            for (int j = 0; j < 4; j++)
                rp[m][j] += __shfl_xor(rp[m][j], mask);

    if (lr == 0) {
        #pragma unroll
        for (int m = 0; m < 4; m++)
            #pragma unroll
            for (int j = 0; j < 4; j++)
                scp[w & 1][wrow + m * 16 + lg * 4 + j] = rp[m][j];
    }
    __syncthreads();
    if (tid < 128)
        wv[tid] = expf(-sqrtf(scp[0][tid] + scp[1][tid]));
    __syncthreads();

    // partial denominator: wave 0 reduces wv[0..127]
    if (w == 0) {
        float d = wv[lane] + wv[lane + 64];
        #pragma unroll
        for (int mask = 1; mask < 64; mask <<= 1)
            d += __shfl_xor(d, mask);
        if (lane == 0) pden[b * 64 + chunk] = d;
    }

    // ---- Phase 2: weighted partial sum over support_y (128 rows x 1000 classes) ----
    if (tid < 250) {
        float a0 = 0.f, a1 = 0.f, a2 = 0.f, a3 = 0.f;
        const float* base = y + ((size_t)b * SS + srow0) * CC + tid * 4;
        #pragma unroll 4
        for (int r = 0; r < 128; r++) {
            float4 v = *(const float4*)(base + (size_t)r * CC);
            float wgt = wv[r];
            a0 += wgt * v.x; a1 += wgt * v.y; a2 += wgt * v.z; a3 += wgt * v.w;
        }
        float4 res = {a0, a1, a2, a3};
        *(float4*)(pout + ((size_t)(b * 64 + chunk)) * CC + tid * 4) = res;
    }
}

// ---------------- K4: final reduction over 64 chunks ----------------
__global__ void k4_final(const float* __restrict__ pout, const float* __restrict__ pden,
                         float* __restrict__ out) {
    int idx = blockIdx.x * 256 + threadIdx.x;
    if (idx >= BB * CC) return;
    int b = idx / CC, c = idx % CC;
    float den = 0.f;
    #pragma unroll 8
    for (int k = 0; k < 64; k++) den += pden[b * 64 + k];
    float num = 0.f;
    #pragma unroll 8
    for (int k = 0; k < 64; k++) num += pout[((size_t)(b * 64 + k)) * CC + c];
    out[idx] = num / den;
}

extern "C" void kernel_launch(void* const* d_in, const int* in_sizes, int n_in,
                              void* d_out, int out_size, void* d_ws, size_t ws_size,
                              hipStream_t stream) {
    const float* x  = (const float*)d_in[0];
    const float* sx = (const float*)d_in[1];
    const float* sy = (const float*)d_in[2];
    const float* W  = (const float*)d_in[3];

    char* ws = (char*)d_ws;
    __bf16* Wt   = (__bf16*)(ws);                        // 131072 B
    float*  pout = (float*)(ws + 131072);                // 2048000 B
    float*  pden = (float*)(ws + 131072 + 2048000);      // 2048 B

    k0_wt<<<256, 256, 0, stream>>>(W, Wt);
    k_fused<<<512, 256, 0, stream>>>(x, sx, Wt, sy, pout, pden);
    k4_final<<<32, 256, 0, stream>>>(pout, pden, (float*)d_out);
}